// Round 6
// baseline (3073.899 us; speedup 1.0000x reference)
//
#include <hip/hip_runtime.h>

typedef __attribute__((ext_vector_type(8))) short bf16x8;
typedef __attribute__((ext_vector_type(4))) float f32x4;

#define T_ 1024

// round-to-nearest-even f32 -> bf16 bits (scalar)
__device__ __forceinline__ unsigned short f2bf(float f) {
  unsigned int u = __float_as_uint(f);
  u += 0x7fffu + ((u >> 16) & 1u);
  return (unsigned short)(u >> 16);
}

// pack 2 f32 -> 2 bf16 (RNE), one instruction
__device__ __forceinline__ unsigned int cvtpk(float a, float b) {
  unsigned int r;
  asm("v_cvt_pk_bf16_f32 %0, %1, %2" : "=v"(r) : "v"(a), "v"(b));
  return r;
}

// tanh(x) = 1 - 2*rcp(1 + exp2(x * 2/ln2)); saturates to +-1, no NaN for finite x
__device__ __forceinline__ float tanh_fast(float x) {
  float e = __builtin_amdgcn_exp2f(x * 2.8853900817779268f);
  return __builtin_fmaf(-2.0f, __builtin_amdgcn_rcpf(1.0f + e), 1.0f);
}

#define BAR() asm volatile("s_waitcnt lgkmcnt(0)\n\ts_barrier" ::: "memory")

// ---- 4 weight matrices [256][256] f32 -> transposed bf16 [u][f], packed at d + w*65536 ----
__global__ __launch_bounds__(256) void k_cvt_w(const float* __restrict__ s0,
                                               const float* __restrict__ s1,
                                               const float* __restrict__ s2,
                                               const float* __restrict__ s3,
                                               unsigned short* __restrict__ d) {
  int w = blockIdx.x >> 8, f = blockIdx.x & 255, u = threadIdx.x;
  const float* s = w == 0 ? s0 : w == 1 ? s1 : w == 2 ? s2 : s3;
  d[w * 65536 + u * 256 + f] = f2bf(s[f * 256 + u]);
}

// ---- C[M x 256] = A[M x 256] @ W + bias, swapped operands (W = MFMA A, rows = MFMA B) ----
// WG = 256 thr (4 waves); block owns 16 A-rows; wave owns n in [64w, 64w+64).
// CVT=1: A is f32 (inline cvt). CVT=0: A already bf16.
template <bool CVT>
__global__ __launch_bounds__(256) void k_gemm(const void* __restrict__ Av,
                                              const unsigned short* __restrict__ WT,
                                              const float* __restrict__ bias,
                                              float* __restrict__ C) {
  const int wave = threadIdx.x >> 6, lane = threadIdx.x & 63;
  const int lo = lane & 15, hi = lane >> 4;
  const int n0 = wave * 64;
  const size_t mt = blockIdx.x;

  bf16x8 a[4][8];
#pragma unroll
  for (int nt = 0; nt < 4; ++nt)
#pragma unroll
    for (int kt = 0; kt < 8; ++kt)
      a[nt][kt] = *(const bf16x8*)(WT + (size_t)(n0 + nt * 16 + lo) * 256 + kt * 32 + hi * 8);

  bf16x8 b[8];
  if (CVT) {
    const float* A = (const float*)Av + (mt * 16 + lo) * 256 + hi * 8;
#pragma unroll
    for (int kt = 0; kt < 8; ++kt) {
      float4 u = *(const float4*)(A + kt * 32);
      float4 v = *(const float4*)(A + kt * 32 + 4);
      union { bf16x8 v8; unsigned int w[4]; } r;
      r.w[0] = cvtpk(u.x, u.y); r.w[1] = cvtpk(u.z, u.w);
      r.w[2] = cvtpk(v.x, v.y); r.w[3] = cvtpk(v.z, v.w);
      b[kt] = r.v8;
    }
  } else {
    const unsigned short* A = (const unsigned short*)Av + (size_t)(mt * 16 + lo) * 256 + hi * 8;
#pragma unroll
    for (int kt = 0; kt < 8; ++kt) b[kt] = *(const bf16x8*)(A + kt * 32);
  }

#pragma unroll
  for (int nt = 0; nt < 4; ++nt) {
    f32x4 acc = *(const f32x4*)(bias + n0 + nt * 16 + hi * 4);
#pragma unroll
    for (int kt = 0; kt < 8; ++kt)
      acc = __builtin_amdgcn_mfma_f32_16x16x32_bf16(a[nt][kt], b[kt], acc, 0, 0, 0);
    *(f32x4*)(C + (size_t)(mt * 16 + lo) * 256 + n0 + nt * 16 + hi * 4) = acc;
  }
}

// ---- recurrent scan, anti-phase teams: h_t = tanh(xp_t + h_{t-1} @ Wh) ----
// 4 WGs x 512 thr. WG = 2 teams x 4 fat waves; team tm owns batch group g = 2*blk + tm
// (16 rows) with its OWN single-buffered 8KB h-tile; each wave owns 64 n (4 M-tiles,
// 32 MFMA/step). Teams share s_barrier but run offset by one half-step:
//   slot: team0 R(t) | team1 W(t-1)   then   team0 W(t) | team1 R(t)
// so each SIMD always has one {ds_read+MFMA} wave and one {tanh+write} wave -> LDS
// bursts overlap compute; barrier doubles as the write->read fence (single buffer OK).
// R = read B-frags + 32 MFMA + xp refill (distance-2, in flight across barriers).
// W = tanh + pack; enc: stream h_t bf16 to hseq; dec: final f32 to out at t=T-1.
template <bool HSEQ>
__global__ __launch_bounds__(512, 2) void k_scan(const float* __restrict__ xp,
                                                 const unsigned short* __restrict__ WhT,
                                                 unsigned short* __restrict__ hseq,
                                                 float* __restrict__ out) {
  __shared__ __align__(16) char hb[16384];  // [team][16 b][256 k] bf16
  const int tid = threadIdx.x, wave = tid >> 6, lane = tid & 63;
  const int team = wave >> 2, tw = wave & 3;
  const int lo = lane & 15, hi = lane >> 4;
  const int g = blockIdx.x * 2 + team;  // batch group (16 rows)
  const int n0 = tw * 64;               // wave's n-range [n0, n0+64)
  char* tb = hb + team * 8192;

  // A-frags (weights), VGPR-resident: row n = n0 + nt*16 + lo, k contiguous
  bf16x8 ah[4][8];
#pragma unroll
  for (int nt = 0; nt < 4; ++nt)
#pragma unroll
    for (int kt = 0; kt < 8; ++kt)
      ah[nt][kt] = *(const bf16x8*)(WhT + (size_t)(n0 + nt * 16 + lo) * 256 + kt * 32 + hi * 8);

  // zero both tiles (t=0 reads zeros = h0)
  for (int i = tid; i < 4096; i += 512) ((unsigned int*)hb)[i] = 0;
  __syncthreads();

  // LDS byte addrs (step-invariant), XOR swizzle bits 4-6
  const int swz = (lo & 7) << 4;
  int raddr[8];
#pragma unroll
  for (int kt = 0; kt < 8; ++kt) raddr[kt] = (lo * 512 + kt * 64 + hi * 16) ^ swz;
  int waddr[4];
#pragma unroll
  for (int nt = 0; nt < 4; ++nt)
    waddr[nt] = (lo * 512 + (n0 + nt * 16 + hi * 4) * 2) ^ swz;

  // global bases: thread touches (b = g*16+lo, n = n0 + hi*4 + nt*16)
  const size_t brow = (size_t)(g * 16 + lo);
  const float* xpw = xp + brow * T_ * 256 + n0 + hi * 4;
  unsigned short* hsp = HSEQ ? (hseq + brow * T_ * 256 + n0 + hi * 4) : nullptr;

  // distance-2 register prefetch of xp (parity reg sets, statically selected)
  f32x4 xva[4], xvb[4];
#pragma unroll
  for (int nt = 0; nt < 4; ++nt) {
    xva[nt] = *(const f32x4*)(xpw + nt * 16);
    xvb[nt] = *(const f32x4*)(xpw + 256 + nt * 16);
  }

  f32x4 c[4];  // pre-activation, carried R -> W across one barrier

  auto R = [&](int t, f32x4 (&xv)[4]) {
    bf16x8 b[8];
#pragma unroll
    for (int kt = 0; kt < 8; ++kt) b[kt] = *(const bf16x8*)(tb + raddr[kt]);
#pragma unroll
    for (int nt = 0; nt < 4; ++nt) c[nt] = xv[nt];
#pragma unroll
    for (int kt = 0; kt < 8; ++kt)
#pragma unroll
      for (int nt = 0; nt < 4; ++nt)
        c[nt] = __builtin_amdgcn_mfma_f32_16x16x32_bf16(ah[nt][kt], b[kt], c[nt], 0, 0, 0);
    // refill this parity for t+2 (stays in flight; barriers never drain vmcnt)
    const int tn = (t + 2 <= T_ - 1) ? t + 2 : T_ - 1;
#pragma unroll
    for (int nt = 0; nt < 4; ++nt)
      xv[nt] = *(const f32x4*)(xpw + (size_t)tn * 256 + nt * 16);
  };

  auto W = [&](int t) {
    float th[16];
#pragma unroll
    for (int nt = 0; nt < 4; ++nt)
#pragma unroll
      for (int j = 0; j < 4; ++j) th[nt * 4 + j] = tanh_fast(c[nt][j]);
    unsigned int pk[8];
#pragma unroll
    for (int nt = 0; nt < 4; ++nt) {
      pk[nt * 2 + 0] = cvtpk(th[nt * 4 + 0], th[nt * 4 + 1]);
      pk[nt * 2 + 1] = cvtpk(th[nt * 4 + 2], th[nt * 4 + 3]);
    }
    if (HSEQ) {  // stream h_t (bf16), stays in flight across steps
#pragma unroll
      for (int nt = 0; nt < 4; ++nt) {
        uint2 w = {pk[nt * 2], pk[nt * 2 + 1]};
        *(uint2*)(hsp + (size_t)t * 256 + nt * 16) = w;
      }
    } else if (t == T_ - 1) {  // final hidden state, f32 [128][256]
      float* op = out + brow * 256 + n0 + hi * 4;
#pragma unroll
      for (int nt = 0; nt < 4; ++nt) {
        f32x4 o = {th[nt * 4], th[nt * 4 + 1], th[nt * 4 + 2], th[nt * 4 + 3]};
        *(f32x4*)(op + nt * 16) = o;
      }
    }
#pragma unroll
    for (int nt = 0; nt < 4; ++nt) {
      uint2 w = {pk[nt * 2], pk[nt * 2 + 1]};
      *(uint2*)(tb + waddr[nt]) = w;
    }
  };

  // anti-phase schedule, 2 barriers/step; all waves hit identical barrier counts
  for (int t = 0; t < T_; t += 2) {
    if (team == 0) R(t, xva); else if (t > 0) W(t - 1);
    BAR();
    if (team == 0) W(t); else R(t, xva);
    BAR();
    if (team == 0) R(t + 1, xvb); else W(t);
    BAR();
    if (team == 0) W(t + 1); else R(t + 1, xvb);
    BAR();
  }
  if (team == 1) W(T_ - 1);  // drain (no barrier needed; kernel ends)
}

extern "C" void kernel_launch(void* const* d_in, const int* in_sizes, int n_in,
                              void* d_out, int out_size, void* d_ws, size_t ws_size,
                              hipStream_t stream) {
  const float* x      = (const float*)d_in[0];
  const float* enc_Wx = (const float*)d_in[1];
  const float* enc_Wh = (const float*)d_in[2];
  const float* enc_b  = (const float*)d_in[3];
  const float* dec_Wx = (const float*)d_in[4];
  const float* dec_Wh = (const float*)d_in[5];
  const float* dec_b  = (const float*)d_in[6];

  char* ws = (char*)d_ws;
  float*          xpe  = (float*)ws;                                  // 128MB xp_enc
  float*          xpd  = (float*)ws;                                  // reuses xpe (dead by then)
  unsigned short* hseq = (unsigned short*)(ws + ((size_t)128 << 20)); // 64MB bf16 h_seq
  unsigned short* wT   = (unsigned short*)(ws + ((size_t)192 << 20)); // 4 x 128KB bf16 W^T

  // wT layout: [0]=enc_Wx^T  [1]=enc_Wh^T  [2]=dec_Wx^T  [3]=dec_Wh^T
  k_cvt_w<<<1024, 256, 0, stream>>>(enc_Wx, enc_Wh, dec_Wx, dec_Wh, wT);
  // xp_enc = x @ enc_Wx + enc_b  (f32 A converted inline)
  k_gemm<true><<<8192, 256, 0, stream>>>(x, wT, enc_b, xpe);
  // encoder scan -> h_seq (bf16 [B][T][U])
  k_scan<true><<<4, 512, 0, stream>>>(xpe, wT + 65536, hseq, nullptr);
  // xp_dec = h_seq @ dec_Wx + dec_b  (bf16 A; overwrites xpe)
  k_gemm<false><<<8192, 256, 0, stream>>>(hseq, wT + 131072, dec_b, xpd);
  // decoder scan -> final hidden state (f32) to d_out
  k_scan<false><<<4, 512, 0, stream>>>(xpd, wT + 196608, nullptr, (float*)d_out);
}

// Round 7
// 1763.495 us; speedup vs baseline: 1.7431x; 1.7431x over previous
//
#include <hip/hip_runtime.h>

typedef __attribute__((ext_vector_type(8))) short bf16x8;
typedef __attribute__((ext_vector_type(4))) float f32x4;

#define T_ 1024

// round-to-nearest-even f32 -> bf16 bits (scalar)
__device__ __forceinline__ unsigned short f2bf(float f) {
  unsigned int u = __float_as_uint(f);
  u += 0x7fffu + ((u >> 16) & 1u);
  return (unsigned short)(u >> 16);
}

// pack 2 f32 -> 2 bf16 (RNE), one instruction
__device__ __forceinline__ unsigned int cvtpk(float a, float b) {
  unsigned int r;
  asm("v_cvt_pk_bf16_f32 %0, %1, %2" : "=v"(r) : "v"(a), "v"(b));
  return r;
}

// tanh(x) = 1 - 2*rcp(1 + exp2(x * 2/ln2)); saturates to +-1, no NaN for finite x
__device__ __forceinline__ float tanh_fast(float x) {
  float e = __builtin_amdgcn_exp2f(x * 2.8853900817779268f);
  return __builtin_fmaf(-2.0f, __builtin_amdgcn_rcpf(1.0f + e), 1.0f);
}

// ---- 4 weight matrices [256][256] f32 -> transposed bf16 [u][f], packed at d + w*65536 ----
__global__ __launch_bounds__(256) void k_cvt_w(const float* __restrict__ s0,
                                               const float* __restrict__ s1,
                                               const float* __restrict__ s2,
                                               const float* __restrict__ s3,
                                               unsigned short* __restrict__ d) {
  int w = blockIdx.x >> 8, f = blockIdx.x & 255, u = threadIdx.x;
  const float* s = w == 0 ? s0 : w == 1 ? s1 : w == 2 ? s2 : s3;
  d[w * 65536 + u * 256 + f] = f2bf(s[f * 256 + u]);
}

// ---- C[M x 256] = A[M x 256] @ W + bias, swapped operands (W = MFMA A, rows = MFMA B) ----
// WG = 256 thr (4 waves); block owns 16 A-rows; wave owns n in [64w, 64w+64).
// CVT=1: A is f32 (inline cvt). CVT=0: A already bf16.
template <bool CVT>
__global__ __launch_bounds__(256) void k_gemm(const void* __restrict__ Av,
                                              const unsigned short* __restrict__ WT,
                                              const float* __restrict__ bias,
                                              float* __restrict__ C) {
  const int wave = threadIdx.x >> 6, lane = threadIdx.x & 63;
  const int lo = lane & 15, hi = lane >> 4;
  const int n0 = wave * 64;
  const size_t mt = blockIdx.x;

  bf16x8 a[4][8];
#pragma unroll
  for (int nt = 0; nt < 4; ++nt)
#pragma unroll
    for (int kt = 0; kt < 8; ++kt)
      a[nt][kt] = *(const bf16x8*)(WT + (size_t)(n0 + nt * 16 + lo) * 256 + kt * 32 + hi * 8);

  bf16x8 b[8];
  if (CVT) {
    const float* A = (const float*)Av + (mt * 16 + lo) * 256 + hi * 8;
#pragma unroll
    for (int kt = 0; kt < 8; ++kt) {
      float4 u = *(const float4*)(A + kt * 32);
      float4 v = *(const float4*)(A + kt * 32 + 4);
      union { bf16x8 v8; unsigned int w[4]; } r;
      r.w[0] = cvtpk(u.x, u.y); r.w[1] = cvtpk(u.z, u.w);
      r.w[2] = cvtpk(v.x, v.y); r.w[3] = cvtpk(v.z, v.w);
      b[kt] = r.v8;
    }
  } else {
    const unsigned short* A = (const unsigned short*)Av + (size_t)(mt * 16 + lo) * 256 + hi * 8;
#pragma unroll
    for (int kt = 0; kt < 8; ++kt) b[kt] = *(const bf16x8*)(A + kt * 32);
  }

#pragma unroll
  for (int nt = 0; nt < 4; ++nt) {
    f32x4 acc = *(const f32x4*)(bias + n0 + nt * 16 + hi * 4);
#pragma unroll
    for (int kt = 0; kt < 8; ++kt)
      acc = __builtin_amdgcn_mfma_f32_16x16x32_bf16(a[nt][kt], b[kt], acc, 0, 0, 0);
    *(f32x4*)(C + (size_t)(mt * 16 + lo) * 256 + n0 + nt * 16 + hi * 4) = acc;
  }
}

// ---- recurrent scan: h_t = tanh(xp_t + h_{t-1} @ Wh), r3 structure + compressed tail ----
// 8 WGs x 512 thr (8 waves, 2/SIMD); WG owns 16 batch rows; wave owns n in [32w,32w+32)
// (2 M-tiles). Weights VGPR-resident. h tile [16 b][256 k] bf16 in LDS, double-buffered,
// XOR-swizzled. One raw lgkm-only barrier per step (xp prefetch distance-2 and all
// global stores stay in flight across steps).
// Tail compression vs r3: (a) K-chains split even/odd kt -> 4 independent depth-4 MFMA
// chains (dep tail ~halved), (b) tile0's tanh+LDS-write issued before tile1's epilogue
// so trans-pipe work overlaps matrix-pipe work, (c) global stores after LDS writes.
// HSEQ=1 (encoder): streams h_t bf16 to hseq. HSEQ=0 (decoder): final f32 out at T-1.
template <bool HSEQ>
__global__ __launch_bounds__(512, 2) void k_scan(const float* __restrict__ xp,
                                                 const unsigned short* __restrict__ WhT,
                                                 unsigned short* __restrict__ hseq,
                                                 float* __restrict__ out) {
  __shared__ __align__(16) char hb[16384];  // [2][16 b][256 k] bf16
  const int tid = threadIdx.x, wave = tid >> 6, lane = tid & 63;
  const int lo = lane & 15, hi = lane >> 4;
  const int wg = blockIdx.x;
  const int n0 = wave * 32;  // wave's n-range [n0, n0+32)

  // A-frags (weights), VGPR-resident: row n = n0 + nt*16 + lo, k contiguous
  bf16x8 ah[2][8];
#pragma unroll
  for (int nt = 0; nt < 2; ++nt)
#pragma unroll
    for (int kt = 0; kt < 8; ++kt)
      ah[nt][kt] = *(const bf16x8*)(WhT + (size_t)(n0 + nt * 16 + lo) * 256 + kt * 32 + hi * 8);

  // zero both h buffers (t=0 reads zeros = h0)
  for (int i = tid; i < 4096; i += 512) ((unsigned int*)hb)[i] = 0;
  __syncthreads();

  // LDS byte addrs (step-invariant), XOR swizzle bits 4-6
  const int swz = (lo & 7) << 4;
  int raddr[8];
#pragma unroll
  for (int kt = 0; kt < 8; ++kt) raddr[kt] = (lo * 512 + kt * 64 + hi * 16) ^ swz;
  int waddr[2];
#pragma unroll
  for (int nt = 0; nt < 2; ++nt)
    waddr[nt] = (lo * 512 + (n0 + nt * 16 + hi * 4) * 2) ^ swz;

  // global bases: thread touches (b = wg*16+lo, n = n0 + hi*4 + nt*16)
  const size_t brow = (size_t)(wg * 16 + lo);
  const float* xpw = xp + brow * T_ * 256 + n0 + hi * 4;
  unsigned short* hsp = HSEQ ? (hseq + brow * T_ * 256 + n0 + hi * 4) : nullptr;

  // distance-2 register prefetch of xp
  f32x4 xva[2], xvb[2];
#pragma unroll
  for (int nt = 0; nt < 2; ++nt) {
    xva[nt] = *(const f32x4*)(xpw + nt * 16);
    xvb[nt] = *(const f32x4*)(xpw + 256 + nt * 16);
  }

  auto step = [&](int t, f32x4 (&xv)[2], int ro, int wo) {
    // B-frags of h_{t-1}
    bf16x8 b[8];
#pragma unroll
    for (int kt = 0; kt < 8; ++kt) b[kt] = *(const bf16x8*)(hb + ro + raddr[kt]);
    // 4 independent depth-4 MFMA chains (even/odd kt per tile), issue order = read order
    f32x4 c0a = xv[0], c1a = xv[1];
    f32x4 c0b = {0.f, 0.f, 0.f, 0.f}, c1b = {0.f, 0.f, 0.f, 0.f};
#pragma unroll
    for (int k2 = 0; k2 < 4; ++k2) {
      c0a = __builtin_amdgcn_mfma_f32_16x16x32_bf16(ah[0][2 * k2], b[2 * k2], c0a, 0, 0, 0);
      c0b = __builtin_amdgcn_mfma_f32_16x16x32_bf16(ah[0][2 * k2 + 1], b[2 * k2 + 1], c0b, 0, 0, 0);
      c1a = __builtin_amdgcn_mfma_f32_16x16x32_bf16(ah[1][2 * k2], b[2 * k2], c1a, 0, 0, 0);
      c1b = __builtin_amdgcn_mfma_f32_16x16x32_bf16(ah[1][2 * k2 + 1], b[2 * k2 + 1], c1b, 0, 0, 0);
    }
    // refill this parity for t+2 (stays in flight; barrier never drains vmcnt)
    {
      const int tn = (t + 2 <= T_ - 1) ? t + 2 : T_ - 1;
#pragma unroll
      for (int nt = 0; nt < 2; ++nt)
        xv[nt] = *(const f32x4*)(xpw + (size_t)tn * 256 + nt * 16);
    }
    // tile0 epilogue first (trans-pipe tanh overlaps tile1's matrix-pipe retire)
    f32x4 z0 = c0a + c0b;
    float t0[4];
#pragma unroll
    for (int j = 0; j < 4; ++j) t0[j] = tanh_fast(z0[j]);
    uint2 w0 = {cvtpk(t0[0], t0[1]), cvtpk(t0[2], t0[3])};
    *(uint2*)(hb + wo + waddr[0]) = w0;
    // tile1 epilogue
    f32x4 z1 = c1a + c1b;
    float t1[4];
#pragma unroll
    for (int j = 0; j < 4; ++j) t1[j] = tanh_fast(z1[j]);
    uint2 w1 = {cvtpk(t1[0], t1[1]), cvtpk(t1[2], t1[3])};
    *(uint2*)(hb + wo + waddr[1]) = w1;
    // global stores last (in flight across the lgkm-only barrier)
    if (HSEQ) {
      *(uint2*)(hsp + (size_t)t * 256) = w0;
      *(uint2*)(hsp + (size_t)t * 256 + 16) = w1;
    } else if (t == T_ - 1) {
      float* op = out + brow * 256 + n0 + hi * 4;
      f32x4 o0 = {t0[0], t0[1], t0[2], t0[3]};
      f32x4 o1 = {t1[0], t1[1], t1[2], t1[3]};
      *(f32x4*)(op) = o0;
      *(f32x4*)(op + 16) = o1;
    }
    // LDS writes visible, then barrier; globals never drained
    asm volatile("s_waitcnt lgkmcnt(0)\n\ts_barrier" ::: "memory");
  };

  for (int t = 0; t < T_; t += 2) {
    step(t, xva, 8192, 0);      // even: read buf1, write buf0
    step(t + 1, xvb, 0, 8192);  // odd:  read buf0, write buf1
  }
}

extern "C" void kernel_launch(void* const* d_in, const int* in_sizes, int n_in,
                              void* d_out, int out_size, void* d_ws, size_t ws_size,
                              hipStream_t stream) {
  const float* x      = (const float*)d_in[0];
  const float* enc_Wx = (const float*)d_in[1];
  const float* enc_Wh = (const float*)d_in[2];
  const float* enc_b  = (const float*)d_in[3];
  const float* dec_Wx = (const float*)d_in[4];
  const float* dec_Wh = (const float*)d_in[5];
  const float* dec_b  = (const float*)d_in[6];

  char* ws = (char*)d_ws;
  float*          xpe  = (float*)ws;                                  // 128MB xp_enc
  float*          xpd  = (float*)ws;                                  // reuses xpe (dead by then)
  unsigned short* hseq = (unsigned short*)(ws + ((size_t)128 << 20)); // 64MB bf16 h_seq
  unsigned short* wT   = (unsigned short*)(ws + ((size_t)192 << 20)); // 4 x 128KB bf16 W^T

  // wT layout: [0]=enc_Wx^T  [1]=enc_Wh^T  [2]=dec_Wx^T  [3]=dec_Wh^T
  k_cvt_w<<<1024, 256, 0, stream>>>(enc_Wx, enc_Wh, dec_Wx, dec_Wh, wT);
  // xp_enc = x @ enc_Wx + enc_b  (f32 A converted inline)
  k_gemm<true><<<8192, 256, 0, stream>>>(x, wT, enc_b, xpe);
  // encoder scan -> h_seq (bf16 [B][T][U])
  k_scan<true><<<8, 512, 0, stream>>>(xpe, wT + 65536, hseq, nullptr);
  // xp_dec = h_seq @ dec_Wx + dec_b  (bf16 A; overwrites xpe)
  k_gemm<false><<<8192, 256, 0, stream>>>(hseq, wT + 131072, dec_b, xpd);
  // decoder scan -> final hidden state (f32) to d_out
  k_scan<false><<<8, 512, 0, stream>>>(xpd, wT + 196608, nullptr, (float*)d_out);
}